// Round 14
// baseline (414.474 us; speedup 1.0000x reference)
//
#include <hip/hip_runtime.h>

// GRU trajectory decoder. B=16384, D=256, HID=128, T=60, O=3.
// R14: wave-autonomous restructure -- NO barrier in the 60-step loop.
// Each wave owns 16 batch rows and computes ALL 384 gate dims itself:
//  - W_hh staged once in LDS (96KB, MFMA A-frag layout, gate-prescaled),
//    read-shared by the block's 4 waves (96 ds_read_b128/wave/step).
//  - h round-trips through a wave-PRIVATE 4KB double-buffered LDS B-frag
//    buffer; same-wave lgkmcnt ordering only (compiler-inserted).
//  - gi (24 m-tiles x f32x4 = 96 VGPRs) + h-state (32) + biases in regs:
//    1 wave/SIMD (launch_bounds(256,1)) -> 512-reg budget, no spill.
// Rationale: R4-R13 showed ~50% of cycles are latency exposed by the
// inter-wave lockstep barrier; issue-count cuts paid 1:1, schedule reorgs
// inside the lockstep did nothing. This removes the lockstep entirely.
// Gate math (validated): R/Z prescaled -log2e, n prescaled -2log2e, hardware
// rcp (R12/R13: Newton strictly worse), shared-rcp sigmoid pair, f32x4 ops,
// v_cvt_pk_bf16_f32 writeback.

typedef __attribute__((ext_vector_type(8))) short short8;
typedef __attribute__((ext_vector_type(4))) float f32x4;

#define MFMA16(a, b, c) __builtin_amdgcn_mfma_f32_16x16x32_bf16((a), (b), (c), 0, 0, 0)
#define ex2  __builtin_amdgcn_exp2f
#define rcpf __builtin_amdgcn_rcpf

__device__ __forceinline__ short f2bf(float x) {
    union { float f; unsigned u; } v; v.f = x;
    unsigned r = v.u + 0x7FFFu + ((v.u >> 16) & 1u);   // RNE
    return (short)(r >> 16);
}

__device__ __forceinline__ unsigned cvtpk(float lo, float hi) {
    unsigned d;
    asm("v_cvt_pk_bf16_f32 %0, %1, %2" : "=v"(d) : "v"(lo), "v"(hi));
    return d;
}

__device__ __forceinline__ short8 cvt8(const float* __restrict__ p) {
    f32x4 a = *(const f32x4*)p;
    f32x4 b = *(const f32x4*)(p + 4);
    short8 r;
    r[0] = f2bf(a[0]); r[1] = f2bf(a[1]); r[2] = f2bf(a[2]); r[3] = f2bf(a[3]);
    r[4] = f2bf(b[0]); r[5] = f2bf(b[1]); r[6] = f2bf(b[2]); r[7] = f2bf(b[3]);
    return r;
}
__device__ __forceinline__ short8 cvt8s(const float* __restrict__ p, float s) {
    f32x4 a = *(const f32x4*)p;
    f32x4 b = *(const f32x4*)(p + 4);
    short8 r;
    r[0] = f2bf(a[0] * s); r[1] = f2bf(a[1] * s); r[2] = f2bf(a[2] * s); r[3] = f2bf(a[3] * s);
    r[4] = f2bf(b[0] * s); r[5] = f2bf(b[1] * s); r[6] = f2bf(b[2] * s); r[7] = f2bf(b[3] * s);
    return r;
}

__global__ __launch_bounds__(256, 1) void gru_traj_kernel(
    const float* __restrict__ x,      // [B,256]
    const float* __restrict__ W_ih,   // [384,256]
    const float* __restrict__ W_hh,   // [384,128]
    const float* __restrict__ b_ih,   // [384]
    const float* __restrict__ b_hh,   // [384]
    const float* __restrict__ W_out,  // [3,128]
    const float* __restrict__ b_out,  // [3]
    float* __restrict__ out)          // [B,60,3]
{
    const int tid  = threadIdx.x;
    const int wid  = tid >> 6;                      // wave 0..3
    const int lane = tid & 63;
    const int l15  = lane & 15;
    const int l4   = lane >> 4;                     // 0..3
    const int bw   = (blockIdx.x << 6) + (wid << 4);// wave's 16 batch rows

    const float SCL  = -1.442695041f;   // -log2(e)   (r/z gates)
    const float SCL2 = -2.885390082f;   // -2*log2(e) (n gate)

    // W_hh in A-frag layout, prescaled: frag f = (g*8+hm)*4+kt; lane l holds
    // W_hh[g*128+hm*16+(l&15)][kt*32+(l>>4)*8 .. +8]*scale(g). 96KB.
    __shared__ short whh_lds[96 * 512];
    // wave-private h B-frag double buffer: [wave][buf][2048 bf16] = 32KB.
    __shared__ short h_lds[4][2][2048];
    // total LDS = 128KB exactly (1 block/CU).

    // ---- cooperative W_hh stage (24 frags per wave) ----
    #pragma unroll
    for (int i = 0; i < 24; ++i) {
        const int f  = wid * 24 + i;
        const int g  = f >> 5, hm = (f >> 2) & 7, kt = f & 3;
        const float s = (g == 2) ? SCL2 : SCL;
        *(short8*)(&whh_lds[f * 512 + lane * 8]) =
            cvt8s(W_hh + (size_t)(g * 128 + hm * 16 + l15) * 128 + kt * 32 + l4 * 8, s);
    }
    // zero own h buf0 (h_0 = 0)
    #pragma unroll
    for (int i = 0; i < 4; ++i)
        *(uint4*)((char*)&h_lds[wid][0][0] + lane * 16 + i * 1024) = uint4{0, 0, 0, 0};

    // W_out A-frags in regs (rows m>=3 zero)
    short8 wofrag[4];
    #pragma unroll
    for (int kt = 0; kt < 4; ++kt) {
        short8 fzero = {0, 0, 0, 0, 0, 0, 0, 0};
        wofrag[kt] = (l15 < 3) ? cvt8(W_out + l15 * 128 + kt * 32 + l4 * 8) : fzero;
    }
    const float bo0 = b_out[0], bo1 = b_out[1], bo2 = b_out[2];

    // n-gate hidden bias (prescaled), per hm: lane's 4 hid dims
    f32x4 bNh[8];
    #pragma unroll
    for (int hm = 0; hm < 8; ++hm)
        bNh[hm] = *(const f32x4*)(b_hh + 256 + hm * 16 + l4 * 4) * SCL2;

    // ---- prologue: gi = W_ih * x^T for ALL 24 m-tiles (prescaled) ----
    short8 bx[8];
    #pragma unroll
    for (int k8 = 0; k8 < 8; ++k8)
        bx[k8] = cvt8(x + (size_t)(bw + l15) * 256 + k8 * 32 + l4 * 8);

    f32x4 giR[8], giZ[8], giN8[8];
    #pragma unroll
    for (int hm = 0; hm < 8; ++hm) {
        const int j = hm * 16 + l4 * 4;
        f32x4 aR = (*(const f32x4*)(b_ih + j)       + *(const f32x4*)(b_hh + j))       * SCL;
        f32x4 aZ = (*(const f32x4*)(b_ih + 128 + j) + *(const f32x4*)(b_hh + 128 + j)) * SCL;
        f32x4 aN = *(const f32x4*)(b_ih + 256 + j) * SCL2;
        #pragma unroll
        for (int k8 = 0; k8 < 8; ++k8) {
            aR = MFMA16(cvt8s(W_ih + (size_t)(      hm * 16 + l15) * 256 + k8 * 32 + l4 * 8, SCL ), bx[k8], aR);
            aZ = MFMA16(cvt8s(W_ih + (size_t)(128 + hm * 16 + l15) * 256 + k8 * 32 + l4 * 8, SCL ), bx[k8], aZ);
            aN = MFMA16(cvt8s(W_ih + (size_t)(256 + hm * 16 + l15) * 256 + k8 * 32 + l4 * 8, SCL2), bx[k8], aN);
        }
        giR[hm] = aR; giZ[hm] = aZ; giN8[hm] = aN;
    }

    f32x4 hst[8];
    #pragma unroll
    for (int hm = 0; hm < 8; ++hm) hst[hm] = (f32x4){0.f, 0.f, 0.f, 0.f};

    __syncthreads();   // whh_lds ready (ONLY barrier; none in the step loop)

    const char* whhB = (const char*)whh_lds;
    char*       hB   = (char*)&h_lds[wid][0][0];
    const int   lofs = lane * 16;
    // h write-back address: lane holds h[batch l15][hid hm*16 + l4*4 .. +4];
    // B-frag target byte addr = l15*16 + (l4>>1)*256 + (l4&1)*8 + hm*512.
    const int   wofs = l15 * 16 + (l4 >> 1) * 256 + (l4 & 1) * 8;

    #pragma unroll 2
    for (int t = 0; t < 60; ++t) {
        const char* hc = hB + (t & 1) * 4096;
        char*       hx = hB + ((t & 1) ^ 1) * 4096;

        short8 af[4];
        #pragma unroll
        for (int kt = 0; kt < 4; ++kt)
            af[kt] = *(const short8*)(hc + kt * 1024 + lofs);

        // output head: out column t-1 from h_t (no rotation needed)
        if (t > 0) {
            f32x4 oa = (f32x4){0.f, 0.f, 0.f, 0.f};
            #pragma unroll
            for (int kt = 0; kt < 4; ++kt) oa = MFMA16(wofrag[kt], af[kt], oa);
            if (l4 == 0) {
                float* op = out + (size_t)(bw + l15) * 180 + (t - 1) * 3;
                op[0] = oa[0] + bo0; op[1] = oa[1] + bo1; op[2] = oa[2] + bo2;
            }
        }

        #pragma unroll
        for (int hm = 0; hm < 8; ++hm) {
            f32x4 aR = giR[hm], aZ = giZ[hm], aN = bNh[hm];
            #pragma unroll
            for (int kt = 0; kt < 4; ++kt) {
                aR = MFMA16(*(const short8*)(whhB + ((0 * 8 + hm) * 4 + kt) * 1024 + lofs), af[kt], aR);
                aZ = MFMA16(*(const short8*)(whhB + ((1 * 8 + hm) * 4 + kt) * 1024 + lofs), af[kt], aZ);
                aN = MFMA16(*(const short8*)(whhB + ((2 * 8 + hm) * 4 + kt) * 1024 + lofs), af[kt], aN);
            }
            // gates (prescaled: exp2 direct), shared-rcp sigmoid pair
            f32x4 eA, eB;
            #pragma unroll
            for (int r = 0; r < 4; ++r) { eA[r] = ex2(aR[r]); eB[r] = ex2(aZ[r]); }
            f32x4 A  = eA + 1.0f;
            f32x4 Bv = eB + 1.0f;
            f32x4 P  = A * Bv;
            f32x4 Rc;
            #pragma unroll
            for (int r = 0; r < 4; ++r) Rc[r] = rcpf(P[r]);
            f32x4 rr = Rc * Bv;
            f32x4 zz = Rc * A;
            f32x4 sn = rr * aN + giN8[hm];
            f32x4 eC;
            #pragma unroll
            for (int r = 0; r < 4; ++r) eC[r] = ex2(sn[r]);
            f32x4 C1 = eC + 1.0f;
            f32x4 T;
            #pragma unroll
            for (int r = 0; r < 4; ++r) T[r] = rcpf(C1[r]);
            f32x4 nn = 2.0f * T - 1.0f;
            f32x4 hn = (hst[hm] - nn) * zz + nn;
            hst[hm] = hn;
            uint2 pk;
            pk.x = cvtpk(hn[0], hn[1]);
            pk.y = cvtpk(hn[2], hn[3]);
            *(uint2*)(hx + wofs + hm * 512) = pk;
        }
        // same-wave RAW on h_lds: compiler inserts lgkmcnt; no s_barrier.
    }

    // epilogue: out column 59 from h_60 (buf 0, since 60 is even)
    {
        const char* hc = hB;
        f32x4 oa = (f32x4){0.f, 0.f, 0.f, 0.f};
        #pragma unroll
        for (int kt = 0; kt < 4; ++kt)
            oa = MFMA16(wofrag[kt], *(const short8*)(hc + kt * 1024 + lofs), oa);
        if (l4 == 0) {
            float* op = out + (size_t)(bw + l15) * 180 + 59 * 3;
            op[0] = oa[0] + bo0; op[1] = oa[1] + bo1; op[2] = oa[2] + bo2;
        }
    }
}

extern "C" void kernel_launch(void* const* d_in, const int* in_sizes, int n_in,
                              void* d_out, int out_size, void* d_ws, size_t ws_size,
                              hipStream_t stream) {
    const float* x     = (const float*)d_in[0];
    const float* W_ih  = (const float*)d_in[1];
    const float* W_hh  = (const float*)d_in[2];
    const float* b_ih  = (const float*)d_in[3];
    const float* b_hh  = (const float*)d_in[4];
    const float* W_out = (const float*)d_in[5];
    const float* b_out = (const float*)d_in[6];
    float* out = (float*)d_out;

    const int B = in_sizes[0] / 256;   // 16384
    hipLaunchKernelGGL(gru_traj_kernel, dim3(B / 64), dim3(256), 0, stream,
                       x, W_ih, W_hh, b_ih, b_hh, W_out, b_out, out);
}

// Round 15
// 146.808 us; speedup vs baseline: 2.8233x; 2.8233x over previous
//
#include <hip/hip_runtime.h>

// GRU trajectory decoder, fused single kernel. B=16384, D=256, HID=128, T=60, O=3.
// R15 = champion restore (R10, 149.7us) + n-gate -2log2e prescale (strictly
// -16 v_mul/wave/step; absmax-neutral per R12/R13).
// Final structure after 14 rounds of measurement:
//  - 512 thr (8 waves), 64 batch rows/block, grid=256 = 1 block/CU, one round;
//    wave owns hid [16w,16w+16): W_hh frags 48 regs, gi as MFMA C-init.
//  - 2 waves/SIMD is register-forced: every occupancy push (R2/R6/R7) spilled;
//    wave-autonomous no-barrier design (R14) spilled AND lost all TLP (414us).
//  - h exchanged via double-buffered XOR-swizzled LDS tile, lgkm-only barrier.
//  - gates: R/Z prescaled -log2e, n prescaled -2log2e (exp2 direct on MFMA
//    out), shared-rcp sigmoid pair (trans floor: 3 exp2 + 2 rcp per elem),
//    hardware rcp (Newton strictly worse, R12/R13), f32x4 algebra,
//    v_cvt_pk_bf16_f32 writeback, alternating af buffers, loop-invariant
//    swizzled LDS byte offsets.
// Measured plateau: ~170us rocprof = per-SIMD issue (~3800cy VALU+trans at
// 16cy/trans) + LDS h-broadcast service (~1540cy/CU) + MFMA occupancy +
// barrier skew, overlapped by only 2 waves/SIMD.

typedef __attribute__((ext_vector_type(8))) short short8;
typedef __attribute__((ext_vector_type(4))) float f32x4;

#define MFMA16(a, b, c) __builtin_amdgcn_mfma_f32_16x16x32_bf16((a), (b), (c), 0, 0, 0)

// LDS-only release barrier: order ds ops, skip vmcnt/expcnt drain.
#define LDS_BARRIER() asm volatile("s_waitcnt lgkmcnt(0)\n\ts_barrier" ::: "memory")

#define ex2  __builtin_amdgcn_exp2f
#define rcpf __builtin_amdgcn_rcpf

__device__ __forceinline__ short f2bf(float x) {
    union { float f; unsigned u; } v; v.f = x;
    unsigned r = v.u + 0x7FFFu + ((v.u >> 16) & 1u);   // RNE
    return (short)(r >> 16);
}

__device__ __forceinline__ unsigned cvtpk(float lo, float hi) {
    unsigned d;
    asm("v_cvt_pk_bf16_f32 %0, %1, %2" : "=v"(d) : "v"(lo), "v"(hi));
    return d;
}

__device__ __forceinline__ short8 cvt8(const float* __restrict__ p) {
    f32x4 a = *(const f32x4*)p;
    f32x4 b = *(const f32x4*)(p + 4);
    short8 r;
    r[0] = f2bf(a[0]); r[1] = f2bf(a[1]); r[2] = f2bf(a[2]); r[3] = f2bf(a[3]);
    r[4] = f2bf(b[0]); r[5] = f2bf(b[1]); r[6] = f2bf(b[2]); r[7] = f2bf(b[3]);
    return r;
}
// scaled variant (fold gate prescales into weights)
__device__ __forceinline__ short8 cvt8s(const float* __restrict__ p, float s) {
    f32x4 a = *(const f32x4*)p;
    f32x4 b = *(const f32x4*)(p + 4);
    short8 r;
    r[0] = f2bf(a[0] * s); r[1] = f2bf(a[1] * s); r[2] = f2bf(a[2] * s); r[3] = f2bf(a[3] * s);
    r[4] = f2bf(b[0] * s); r[5] = f2bf(b[1] * s); r[6] = f2bf(b[2] * s); r[7] = f2bf(b[3] * s);
    return r;
}

__global__ __launch_bounds__(512, 2) void gru_traj_kernel(
    const float* __restrict__ x,      // [B,256]
    const float* __restrict__ W_ih,   // [384,256]
    const float* __restrict__ W_hh,   // [384,128]
    const float* __restrict__ b_ih,   // [384]
    const float* __restrict__ b_hh,   // [384]
    const float* __restrict__ W_out,  // [3,128]
    const float* __restrict__ b_out,  // [3]
    float* __restrict__ out)          // [B,60,3]
{
    const int tid  = threadIdx.x;
    const int wid  = tid >> 6;          // wave 0..7 -> hid chunk [16w,16w+16)
    const int lane = tid & 63;
    const int l15  = lane & 15;
    const int l4   = lane >> 4;         // 0..3
    const int b0   = blockIdx.x << 6;   // 64 batch rows per block
    const int hb   = wid << 4;

    const float SCL  = -1.442695041f;   // -log2(e)   (r/z gates)
    const float SCL2 = -2.885390082f;   // -2*log2(e) (n gate)

    // h^T staging: [64 batch rows][128 hid] bf16, 16B-chunk XOR swizzle, dbuf
    __shared__ short hbuf[2][64 * 128];

    {   // h_0 = 0
        int* z = (int*)hbuf[0];
        #pragma unroll
        for (int i = 0; i < 8; ++i) z[tid + i * 512] = 0;
    }

    // ---- persistent W_hh A-frags: A[m=l15][k] = W_hh[g*128+hb+l15][k]
    short8 wfrag[3][4];
    #pragma unroll
    for (int kt = 0; kt < 4; ++kt) {
        wfrag[0][kt] = cvt8s(W_hh + (size_t)(      hb + l15) * 128 + kt * 32 + l4 * 8, SCL);
        wfrag[1][kt] = cvt8s(W_hh + (size_t)(128 + hb + l15) * 128 + kt * 32 + l4 * 8, SCL);
        wfrag[2][kt] = cvt8s(W_hh + (size_t)(256 + hb + l15) * 128 + kt * 32 + l4 * 8, SCL2);
    }
    // W_out fragments in registers (rows n>=3 zero)
    short8 wofrag[4];
    #pragma unroll
    for (int kt = 0; kt < 4; ++kt) {
        short8 f = {0, 0, 0, 0, 0, 0, 0, 0};
        if (l15 < 3) f = cvt8(W_out + l15 * 128 + kt * 32 + l4 * 8);
        wofrag[kt] = f;
    }

    // biases over this lane's 4 hid dims (D rows l4*4+r); prescaled per gate
    const int bbase = hb + l4 * 4;
    const f32x4 bR4 = (*(const f32x4*)(b_ih + bbase)       + *(const f32x4*)(b_hh + bbase))       * SCL;
    const f32x4 bZ4 = (*(const f32x4*)(b_ih + 128 + bbase) + *(const f32x4*)(b_hh + 128 + bbase)) * SCL;
    const f32x4 bNi = *(const f32x4*)(b_ih + 256 + bbase) * SCL2;
    const f32x4 bNh = *(const f32x4*)(b_hh + 256 + bbase) * SCL2;
    const float bo0 = b_out[0], bo1 = b_out[1], bo2 = b_out[2];

    // ---- prologue: gi^T = W_ih * x^T per batch-chunk q (prescaled) ----
    f32x4 initR[4], initZ[4], giN[4];
    #pragma unroll
    for (int q = 0; q < 4; ++q) { initR[q] = bR4; initZ[q] = bZ4; giN[q] = bNi; }
    #pragma unroll
    for (int kt = 0; kt < 8; ++kt) {
        short8 a0 = cvt8s(W_ih + (size_t)(      hb + l15) * 256 + kt * 32 + l4 * 8, SCL);
        short8 a1 = cvt8s(W_ih + (size_t)(128 + hb + l15) * 256 + kt * 32 + l4 * 8, SCL);
        short8 a2 = cvt8s(W_ih + (size_t)(256 + hb + l15) * 256 + kt * 32 + l4 * 8, SCL2);
        #pragma unroll
        for (int q = 0; q < 4; ++q) {
            short8 bx = cvt8(x + (size_t)(b0 + q * 16 + l15) * 256 + kt * 32 + l4 * 8);
            initR[q] = MFMA16(a0, bx, initR[q]);
            initZ[q] = MFMA16(a1, bx, initZ[q]);
            giN [q] = MFMA16(a2, bx, giN [q]);
        }
    }

    f32x4 hq[4];
    #pragma unroll
    for (int q = 0; q < 4; ++q) hq[q] = (f32x4){0.f, 0.f, 0.f, 0.f};

    // loop-invariant LDS byte offsets (swizzled); in-loop addrs are base+imm
    const int s8 = (wid << 2) | l4;     // lane's 8B slot (hid/4) in an h row
    int roff[4];
    #pragma unroll
    for (int kt = 0; kt < 4; ++kt)
        roff[kt] = (l15 * 128 + (((kt * 4 + l4) ^ l15) & 15) * 8) * 2;
    const int woff = (l15 * 128 + (((s8 >> 1) ^ l15) & 15) * 8 + (s8 & 1) * 4) * 2;

    LDS_BARRIER();

#define LOADQ(buf, q)                                               \
    {                                                               \
        _Pragma("unroll")                                           \
        for (int kt = 0; kt < 4; ++kt)                              \
            buf[kt] = *(const short8*)(rb + roff[kt] + (q) * 4096); \
    }

#define PROCQ(q, AF)                                                          \
    {                                                                         \
        f32x4 aR = initR[q], aZ = initZ[q], aN = bNh;                         \
        _Pragma("unroll")                                                     \
        for (int kt = 0; kt < 4; ++kt) {                                      \
            aR = MFMA16(wfrag[0][kt], AF[kt], aR);                            \
            aZ = MFMA16(wfrag[1][kt], AF[kt], aZ);                            \
            aN = MFMA16(wfrag[2][kt], AF[kt], aN);                            \
        }                                                                     \
        if (t > 0 && wid == (((q) + t) & 7)) {                                \
            f32x4 oa = (f32x4){0.f, 0.f, 0.f, 0.f};                           \
            _Pragma("unroll")                                                 \
            for (int kt = 0; kt < 4; ++kt) oa = MFMA16(wofrag[kt], AF[kt], oa); \
            if (l4 == 0) {                                                    \
                float* op = out + (size_t)(b0 + (q) * 16 + l15) * 180 + (t - 1) * 3; \
                op[0] = oa[0] + bo0; op[1] = oa[1] + bo1; op[2] = oa[2] + bo2; \
            }                                                                 \
        }                                                                     \
        f32x4 eA, eB;                                                         \
        _Pragma("unroll")                                                     \
        for (int r = 0; r < 4; ++r) {                                         \
            eA[r] = ex2(aR[r]);                                               \
            eB[r] = ex2(aZ[r]);                                               \
        }                                                                     \
        f32x4 A  = eA + 1.0f;                                                 \
        f32x4 Bv = eB + 1.0f;                                                 \
        f32x4 P  = A * Bv;                                                    \
        f32x4 R;                                                              \
        _Pragma("unroll")                                                     \
        for (int r = 0; r < 4; ++r) R[r] = rcpf(P[r]);                        \
        f32x4 rr = R * Bv;                                                    \
        f32x4 zz = R * A;                                                     \
        f32x4 sn = rr * aN + giN[q];                                          \
        f32x4 eC;                                                             \
        _Pragma("unroll")                                                     \
        for (int r = 0; r < 4; ++r) eC[r] = ex2(sn[r]);                       \
        f32x4 C1 = eC + 1.0f;                                                 \
        f32x4 T;                                                              \
        _Pragma("unroll")                                                     \
        for (int r = 0; r < 4; ++r) T[r] = rcpf(C1[r]);                       \
        f32x4 nn = 2.0f * T - 1.0f;                                           \
        f32x4 hn = (hq[q] - nn) * zz + nn;                                    \
        hq[q] = hn;                                                           \
        uint2 pk;                                                             \
        pk.x = cvtpk(hn[0], hn[1]);                                           \
        pk.y = cvtpk(hn[2], hn[3]);                                           \
        *(uint2*)(wb + woff + (q) * 4096) = pk;                               \
    }

    #pragma unroll 2
    for (int t = 0; t < 60; ++t) {
        const char* rb = (const char*)hbuf[t & 1];
        char*       wb = (char*)hbuf[(t & 1) ^ 1];

        short8 afA[4], afB[4];
        LOADQ(afA, 0);
        LOADQ(afB, 1);
        PROCQ(0, afA);
        LOADQ(afA, 2);
        PROCQ(1, afB);
        LOADQ(afB, 3);
        PROCQ(2, afA);
        PROCQ(3, afB);

        LDS_BARRIER();
    }

    // epilogue: out column 59 from h_60 (in hbuf[0])
    if (wid < 4) {
        const int q = wid;
        const char* rb = (const char*)hbuf[0];
        f32x4 oa = (f32x4){0.f, 0.f, 0.f, 0.f};
        #pragma unroll
        for (int kt = 0; kt < 4; ++kt) {
            short8 af = *(const short8*)(rb + roff[kt] + q * 4096);
            oa = MFMA16(wofrag[kt], af, oa);
        }
        if (l4 == 0) {
            float* op = out + (size_t)(b0 + q * 16 + l15) * 180 + 59 * 3;
            op[0] = oa[0] + bo0; op[1] = oa[1] + bo1; op[2] = oa[2] + bo2;
        }
    }
#undef LOADQ
#undef PROCQ
}

extern "C" void kernel_launch(void* const* d_in, const int* in_sizes, int n_in,
                              void* d_out, int out_size, void* d_ws, size_t ws_size,
                              hipStream_t stream) {
    const float* x     = (const float*)d_in[0];
    const float* W_ih  = (const float*)d_in[1];
    const float* W_hh  = (const float*)d_in[2];
    const float* b_ih  = (const float*)d_in[3];
    const float* b_hh  = (const float*)d_in[4];
    const float* W_out = (const float*)d_in[5];
    const float* b_out = (const float*)d_in[6];
    float* out = (float*)d_out;

    const int B = in_sizes[0] / 256;   // 16384
    hipLaunchKernelGGL(gru_traj_kernel, dim3(B / 64), dim3(512), 0, stream,
                       x, W_ih, W_hh, b_ih, b_hh, W_out, b_out, out);
}